// Round 8
// baseline (398.967 us; speedup 1.0000x reference)
//
#include <hip/hip_runtime.h>
#include <stdint.h>

#define N_NODES 10000
#define N_EDGES 160000
#define D 512
#define TOT (N_NODES * D)          // 5,120,000
#define NMASK (TOT / 32)           // 160,000 u32 words per dropout mask
#define CAP 64                     // ELL slots/node; P(Poisson(16) > 64) ~ 1e-18
#define MT 16                      // nodes per fused block
#define NBLK_F 625                 // 625 * 16 = 10000 exactly
#define LDA3 520                   // A-slab row stride (halves, 1040B = 16B-aligned)

typedef _Float16 h8 __attribute__((ext_vector_type(8)));
typedef float f4 __attribute__((ext_vector_type(4)));

// ---------------- threefry2x32 (JAX partitionable semantics) ----------------
__host__ __device__ inline uint32_t rotl32(uint32_t v, int r) {
    return (v << r) | (v >> (32 - r));
}

__host__ __device__ inline void tf2x32(uint32_t k0, uint32_t k1,
                                       uint32_t& x0, uint32_t& x1) {
    uint32_t k2 = k0 ^ k1 ^ 0x1BD11BDAu;
    x0 += k0; x1 += k1;
    x0 += x1; x1 = rotl32(x1, 13); x1 ^= x0;
    x0 += x1; x1 = rotl32(x1, 15); x1 ^= x0;
    x0 += x1; x1 = rotl32(x1, 26); x1 ^= x0;
    x0 += x1; x1 = rotl32(x1,  6); x1 ^= x0;
    x0 += k1; x1 += k2 + 1u;
    x0 += x1; x1 = rotl32(x1, 17); x1 ^= x0;
    x0 += x1; x1 = rotl32(x1, 29); x1 ^= x0;
    x0 += x1; x1 = rotl32(x1, 16); x1 ^= x0;
    x0 += x1; x1 = rotl32(x1, 24); x1 ^= x0;
    x0 += k2; x1 += k0 + 2u;
    x0 += x1; x1 = rotl32(x1, 13); x1 ^= x0;
    x0 += x1; x1 = rotl32(x1, 15); x1 ^= x0;
    x0 += x1; x1 = rotl32(x1, 26); x1 ^= x0;
    x0 += x1; x1 = rotl32(x1,  6); x1 ^= x0;
    x0 += k0; x1 += k1 + 3u;
    x0 += x1; x1 = rotl32(x1, 17); x1 ^= x0;
    x0 += x1; x1 = rotl32(x1, 29); x1 ^= x0;
    x0 += x1; x1 = rotl32(x1, 16); x1 ^= x0;
    x0 += x1; x1 = rotl32(x1, 24); x1 ^= x0;
    x0 += k1; x1 += k2 + 4u;
    x0 += x1; x1 = rotl32(x1, 13); x1 ^= x0;
    x0 += x1; x1 = rotl32(x1, 15); x1 ^= x0;
    x0 += x1; x1 = rotl32(x1, 26); x1 ^= x0;
    x0 += x1; x1 = rotl32(x1,  6); x1 ^= x0;
    x0 += k2; x1 += k0 + 5u;
}

__device__ __forceinline__ uint32_t dropout_bit(uint32_t k0, uint32_t k1, uint32_t j) {
    uint32_t c0 = 0u, c1 = j;
    tf2x32(k0, k1, c0, c1);
    uint32_t bits = c0 ^ c1;
    float u = __uint_as_float((bits >> 9) | 0x3f800000u) - 1.0f;
    return (u < 0.8f) ? 1u : 0u;
}

// ---------------- pre1: zero counters + Wt + dropout0 + mask1 + mask2 -------
// All branches independent (zero range not touched by other branches here).
// block ranges: [0,20) zero, [20,212) wconv, [212,5212) dropout0,
// [5212,6462) masks.
#define ZERO_BLKS 20
#define WCONV_BLKS 192
#define DROP_BLKS 5000
#define MASKG_BLKS 625             // NMASK / 256
#define PRE1_BLKS (ZERO_BLKS + WCONV_BLKS + DROP_BLKS + 2 * MASKG_BLKS)
__global__ __launch_bounds__(256)
void pre1_kernel(int* __restrict__ zero_base,      // deg_out..cnt_in (20000 ints)
                 const float* __restrict__ W0, const float* __restrict__ W1,
                 const float* __restrict__ W2, _Float16* __restrict__ Wt,
                 const float* __restrict__ x, _Float16* __restrict__ y,
                 uint32_t k0, uint32_t k1,
                 uint32_t m1k0, uint32_t m1k1, uint32_t* __restrict__ mask1,
                 uint32_t m2k0, uint32_t m2k1, uint32_t* __restrict__ mask2) {
    __shared__ float tile[64][65];
    int b = blockIdx.x;
    int t = threadIdx.x;
    if (b < ZERO_BLKS) {
        int i = b * 256 + t;                       // 5120 int4 = 20480 ints;
        if (i < 5000)                              // write exactly 20000
            *(int4*)&zero_base[i * 4] = make_int4(0, 0, 0, 0);
    } else if (b < ZERO_BLKS + WCONV_BLKS) {
        int b2 = b - ZERO_BLKS;
        int bx = b2 & 7, by = (b2 >> 3) & 7, bz = b2 >> 6;
        const float* W = (bz == 0) ? W0 : (bz == 1) ? W1 : W2;
        _Float16* T = Wt + (size_t)bz * 512 * 512;
        int r0 = by * 64, c0 = bx * 64;
        int c = t & 63, rq = t >> 6;
#pragma unroll
        for (int i = 0; i < 16; ++i) {
            int r = rq + i * 4;
            tile[r][c] = W[(size_t)(r0 + r) * 512 + c0 + c];
        }
        __syncthreads();
        int k = t & 63, nq = t >> 6;
#pragma unroll
        for (int i = 0; i < 16; ++i) {
            int n = nq + i * 4;
            T[(size_t)(c0 + n) * 512 + r0 + k] = (_Float16)tile[k][n];
        }
    } else if (b < ZERO_BLKS + WCONV_BLKS + DROP_BLKS) {
        int b3 = b - ZERO_BLKS - WCONV_BLKS;
        int j = (b3 * 256 + t) * 4;
        if (j >= TOT) return;
        float4 xv = *(const float4*)&x[j];
        _Float16 r[4];
        uint32_t jj = (uint32_t)j;
#pragma unroll
        for (int i = 0; i < 4; ++i) {
            float g = dropout_bit(k0, k1, jj + (uint32_t)i) ? 1.0f : 0.0f;
            float xi = (&xv.x)[i];
            r[i] = (_Float16)(g * (xi * 1.25f));
        }
        *(ushort4*)&y[j] = *(ushort4*)r;
    } else {
        int b4 = b - ZERO_BLKS - WCONV_BLKS - DROP_BLKS;
        int which = b4 / MASKG_BLKS;               // 0 -> mask1, 1 -> mask2
        int gtid = (b4 % MASKG_BLKS) * 256 + t;    // 0..159999 exactly
        uint32_t mk0 = which ? m2k0 : m1k0;
        uint32_t mk1 = which ? m2k1 : m1k1;
        uint32_t* m = which ? mask2 : mask1;
        uint32_t w = 0, jb = (uint32_t)gtid * 32u;
#pragma unroll 4
        for (int i = 0; i < 32; ++i)
            w |= dropout_bit(mk0, mk1, jb + (uint32_t)i) << i;
        m[gtid] = w;
    }
}

// ---------------- pre2: hist(deg_out) + ELL fill in ONE dispatch ------------
// rn_out no longer needed here (applied per-edge in gather from deg_out),
// so hist and fill have no cross-dependency. ELL stores RAW ew.
__global__ __launch_bounds__(256)
void pre2_kernel(const int* __restrict__ src, const int* __restrict__ dst,
                 const float* __restrict__ ew, int* __restrict__ deg_out,
                 int* __restrict__ cnt_in, int2* __restrict__ ell) {
    int e = blockIdx.x * 256 + threadIdx.x;        // grid exactly covers N_EDGES
    int sn = src[e];
    int v = dst[e];
    atomicAdd(&deg_out[sn], 1);
    int pos = atomicAdd(&cnt_in[v], 1);
    if (pos < CAP)
        ell[(size_t)v * CAP + pos] = make_int2(sn, __float_as_int(ew[e]));
}

// ---------------- fused layer v3: occupancy-first ---------------------------
// 625 blocks x 256 thr (4 waves), m-tile = 16 nodes (625*16 = 10000 exact).
// LDS = AT[16][520] 16.6KB + swizzled Bs[512][32] 32.8KB = 49.4KB
//   -> 3 blocks/CU (was 2 at 74KB), grid 2.44 blocks/CU -> ~10-12 waves/CU
//   (r7 measured 6.2 -> the latency-bound gather gets ~2x more in-flight).
// Bs has NO pad; instead chunk swizzle c -> c ^ ((row>>1)&3) within each
// row's 64B. Derivation: row stride 64B = 16 words; per 16-lane phase the
// (row&1)*16 + 4*(c^((row>>1)&3)) start covers 8 distinct bank-quads twice
// -> 2-way = free (m136), on both staging writes and fragment reads.
// Gather applies rn_out per edge: wt = ew * 1/sqrt(max(deg_out[src],1))
// (same f32 expression previously computed in fill -> bit-identical).
__global__ __launch_bounds__(256, 3)
void fused_layer(const _Float16* __restrict__ yin, const int* __restrict__ deg_out,
                 const int* __restrict__ cnt_in, const int2* __restrict__ ell,
                 const _Float16* __restrict__ Wt, const float* __restrict__ bias,
                 const uint32_t* __restrict__ mask,
                 _Float16* __restrict__ yout, float* __restrict__ fout, int mode) {
    __shared__ _Float16 AT[MT * LDA3];   // 16640 B
    __shared__ _Float16 Bs[512 * 32];    // 32768 B (swizzled)
    const int tid = threadIdx.x;
    const int w = tid >> 6, lane = tid & 63;
    const int base = blockIdx.x * MT;
    const _Float16* yl = yin + lane * 8;

    // ---- gather: 4 nodes per wave (4 waves -> 16 rows) ----
    for (int i = 0; i < 4; ++i) {
        int row = w * 4 + i;
        int node = base + row;
        int deg = cnt_in[node];
        if (deg > CAP) deg = CAP;
        const int2* ep = ell + (size_t)node * CAP;
        float acc[8] = {0, 0, 0, 0, 0, 0, 0, 0};
        int k = 0;
        for (; k + 15 < deg; k += 16) {
            int2 e[16];
#pragma unroll
            for (int u = 0; u < 16; ++u) e[u] = ep[k + u];
            h8 v[16];
#pragma unroll
            for (int u = 0; u < 16; ++u) v[u] = *(const h8*)&yl[(size_t)e[u].x * 512];
            float rno[16];
#pragma unroll
            for (int u = 0; u < 16; ++u)
                rno[u] = 1.0f / sqrtf(fmaxf((float)deg_out[e[u].x], 1.0f));
#pragma unroll
            for (int u = 0; u < 16; ++u) {
                float wt = __int_as_float(e[u].y) * rno[u];
#pragma unroll
                for (int j = 0; j < 8; ++j) acc[j] += wt * (float)v[u][j];
            }
        }
        for (; k + 3 < deg; k += 4) {
            int2 e[4];
#pragma unroll
            for (int u = 0; u < 4; ++u) e[u] = ep[k + u];
            h8 v[4];
#pragma unroll
            for (int u = 0; u < 4; ++u) v[u] = *(const h8*)&yl[(size_t)e[u].x * 512];
#pragma unroll
            for (int u = 0; u < 4; ++u) {
                float wt = __int_as_float(e[u].y)
                         * (1.0f / sqrtf(fmaxf((float)deg_out[e[u].x], 1.0f)));
#pragma unroll
                for (int j = 0; j < 8; ++j) acc[j] += wt * (float)v[u][j];
            }
        }
        for (; k < deg; ++k) {
            int2 e0 = ep[k];
            float wt = __int_as_float(e0.y)
                     * (1.0f / sqrtf(fmaxf((float)deg_out[e0.x], 1.0f)));
            h8 v = *(const h8*)&yl[(size_t)e0.x * 512];
#pragma unroll
            for (int j = 0; j < 8; ++j) acc[j] += wt * (float)v[j];
        }
        _Float16 r[8];
#pragma unroll
        for (int j = 0; j < 8; ++j) r[j] = (_Float16)acc[j];
        *(h8*)&AT[row * LDA3 + lane * 8] = *(h8*)r;
    }
    __syncthreads();

    // ---- GEMM: all 4 waves share A rows 0-15; wave w owns cols [w*128,+128)
    f4 acc[8];
#pragma unroll
    for (int i = 0; i < 8; ++i) acc[i] = (f4){0.f, 0.f, 0.f, 0.f};

    // staging: thread t stages Wt rows t and t+256 (32 halves per K-step)
    const _Float16* w0 = Wt + (size_t)tid * 512;
    const _Float16* w1 = Wt + (size_t)(tid + 256) * 512;
    const int sw = (tid >> 1) & 3;       // same for t and t+256 (bit 1-2)
    _Float16* bw0 = &Bs[tid * 32];
    _Float16* bw1 = &Bs[(tid + 256) * 32];
    const _Float16* arow = &AT[(lane & 15) * LDA3 + (lane >> 4) * 8];

    h8 rb0[4], rb1[4];
#pragma unroll
    for (int c = 0; c < 4; ++c) {
        rb0[c] = *(const h8*)(w0 + c * 8);
        rb1[c] = *(const h8*)(w1 + c * 8);
    }

    const int kc = lane >> 4;            // this lane's K-chunk (0..3)
    for (int ks = 0; ks < 16; ++ks) {
#pragma unroll
        for (int c = 0; c < 4; ++c) {
            *(h8*)(bw0 + (c ^ sw) * 8) = rb0[c];
            *(h8*)(bw1 + (c ^ sw) * 8) = rb1[c];
        }
        __syncthreads();
        if (ks < 15) {                   // register prefetch next K-step
            const _Float16* n0 = w0 + (ks + 1) * 32;
            const _Float16* n1 = w1 + (ks + 1) * 32;
#pragma unroll
            for (int c = 0; c < 4; ++c) {
                rb0[c] = *(const h8*)(n0 + c * 8);
                rb1[c] = *(const h8*)(n1 + c * 8);
            }
        }
        h8 a = *(const h8*)(arow + ks * 32);
#pragma unroll
        for (int nt = 0; nt < 8; ++nt) {
            int col = w * 128 + nt * 16 + (lane & 15);
            h8 bf = *(const h8*)&Bs[col * 32 + ((kc ^ ((col >> 1) & 3)) * 8)];
            acc[nt] = __builtin_amdgcn_mfma_f32_16x16x32_f16(a, bf, acc[nt], 0, 0, 0);
        }
        __syncthreads();
    }

    // ---- epilogue. C/D layout: col = lane&15, row = (lane>>4)*4 + reg ----
    const int r0g = (lane >> 4) * 4;
    float rn[4];
#pragma unroll
    for (int i = 0; i < 4; ++i) {
        int d = cnt_in[base + r0g + i];
        rn[i] = 1.0f / sqrtf(fmaxf((float)d, 1.0f));
    }
#pragma unroll
    for (int nt = 0; nt < 8; ++nt) {
        int col = w * 128 + nt * 16 + (lane & 15);
        float bcol = bias[col];
#pragma unroll
        for (int i = 0; i < 4; ++i) {
            int gr = base + r0g + i;
            float v = acc[nt][i] * rn[i] + bcol;
            if (mode == 0) {
                v = (v > 0.f) ? v : (__expf(v) - 1.0f);   // ELU, ~1e-8 vs expm1
                uint32_t j = (uint32_t)(gr * 512 + col);
                uint32_t g = (mask[j >> 5] >> (j & 31)) & 1u;
                v = g ? (v * 1.25f) : 0.0f;
                AT[(r0g + i) * LDA3 + col] = (_Float16)v;
            } else {
                fout[(size_t)gr * 512 + col] = v;
            }
        }
    }

    // ---- coalesced row stores (mode 0) ----
    if (mode == 0) {
        __syncthreads();
#pragma unroll
        for (int i = 0; i < 4; ++i) {
            int c = tid + 256 * i;       // 1024 chunks = 16 rows x 64 h8
            int row = c >> 6, col8 = c & 63;
            *(h8*)&yout[(size_t)(base + row) * 512 + col8 * 8] =
                *(const h8*)&AT[row * LDA3 + col8 * 8];
        }
    }
}

// ---------------- launch: 5 dispatches total --------------------------------
extern "C" void kernel_launch(void* const* d_in, const int* in_sizes, int n_in,
                              void* d_out, int out_size, void* d_ws, size_t ws_size,
                              hipStream_t stream) {
    const float* x   = (const float*)d_in[0];
    const int*   src = (const int*)d_in[1];
    const int*   dst = (const int*)d_in[2];
    const float* ew  = (const float*)d_in[3];
    const float* W0  = (const float*)d_in[4];
    const float* b0  = (const float*)d_in[5];
    const float* W1  = (const float*)d_in[6];
    const float* b1  = (const float*)d_in[7];
    const float* W2  = (const float*)d_in[8];
    const float* b2  = (const float*)d_in[9];
    float* out = (float*)d_out;

    char* ws = (char*)d_ws;
    _Float16* y16  = (_Float16*)ws; ws += (size_t)TOT * 2;            // 10.24 MB
    _Float16* y16b = (_Float16*)ws; ws += (size_t)TOT * 2;            // 10.24 MB
    _Float16* Wt   = (_Float16*)ws; ws += (size_t)3 * 512 * 512 * 2;  // 1.57 MB
    // deg_out + cnt_in contiguous: zeroed by pre1's zero blocks (int4,
    // overrun of <2KB spills harmlessly into the ell head, filled later)
    int* deg_out = (int*)ws;   ws += N_NODES * 4;
    int* cnt_in  = (int*)ws;   ws += N_NODES * 4;
    ws = (char*)(((uintptr_t)ws + 15) & ~(uintptr_t)15);
    int2* ell    = (int2*)ws;  ws += (size_t)N_NODES * CAP * 8;       // 5.12 MB
    uint32_t* mask1 = (uint32_t*)ws; ws += (size_t)NMASK * 4;         // 640 KB
    uint32_t* mask2 = (uint32_t*)ws; ws += (size_t)NMASK * 4;         // 640 KB

    // partitionable split: subkey i = both lanes of cipher(key=(0,42), x0=0, x1=i)
    uint32_t dk[3][2];
    for (int i = 0; i < 3; ++i) {
        uint32_t c0 = 0u, c1 = (uint32_t)i;
        tf2x32(0u, 42u, c0, c1);
        dk[i][0] = c0; dk[i][1] = c1;
    }

    pre1_kernel<<<PRE1_BLKS, 256, 0, stream>>>(deg_out, W0, W1, W2, Wt,
                                               x, y16, dk[0][0], dk[0][1],
                                               dk[1][0], dk[1][1], mask1,
                                               dk[2][0], dk[2][1], mask2);
    pre2_kernel<<<N_EDGES / 256, 256, 0, stream>>>(src, dst, ew, deg_out,
                                                   cnt_in, ell);

    // layer 0: y16 -> y16b ; layer 1: y16b -> y16 ; layer 2: y16 -> out (f32)
    fused_layer<<<NBLK_F, 256, 0, stream>>>(y16, deg_out, cnt_in, ell, Wt,
                                            b0, mask1, y16b, nullptr, 0);
    fused_layer<<<NBLK_F, 256, 0, stream>>>(y16b, deg_out, cnt_in, ell,
                                            Wt + (size_t)512 * 512,
                                            b1, mask2, y16, nullptr, 0);
    fused_layer<<<NBLK_F, 256, 0, stream>>>(y16, deg_out, cnt_in, ell,
                                            Wt + (size_t)2 * 512 * 512,
                                            b2, nullptr, nullptr, out, 1);
}